// Round 2
// 585.257 us; speedup vs baseline: 1.3116x; 1.3116x over previous
//
#include <hip/hip_runtime.h>
#include <float.h>

// ---------------------------------------------------------------------------
// MPNN forward.  msg@w1 decomposed: per-node p=h@w1a, q=h@w1b (fused gemm_pq,
// f16 out, BN fused on A-load), per-edge ea@w1c fp32; edge GEMM t1@w2 f16 MFMA.
// R12 == R11 resubmit (container acquisition failed twice; no kernel verdict).
// R11: node_agg latency attack.  NPB 8->16 (half the blocks, amortize
// prologue/stats), ET 160->128.  Phases A+B merged into a single batched
// issue phase: srcp read per-gather-thread (wave-broadcast, no sidx LDS
// staging), fixed-trip unrolled load batches (4 srcp -> 4 q half8, 2 perm ->
// 2 ea float4) so all misses overlap instead of serializing.  w1c column
// held in 16 VGPRs per lane (channel = lane) instead of LDS -> phase C loses
// its 16 LDS reads/lane/edge.  LDS 42.5KB -> 34.5KB => 4 blocks/CU
// (launch_bounds(256,4)), up from 3.
//
// ws (proven bound 38,601,024 B): hagg 12.8M | pqh 12.8M | ends 200K |
//   srcp 3.2M | part | stats(256f)  = 29.0 MB.
// d_out scratch: perm 3.2M | w2h 16K (both dead before head writes d_out).
// ---------------------------------------------------------------------------

typedef _Float16 half8 __attribute__((ext_vector_type(8)));
typedef _Float16 half4 __attribute__((ext_vector_type(4)));
typedef float floatx4 __attribute__((ext_vector_type(4)));

#define BN_EPS 1e-5f

__device__ __forceinline__ unsigned enc(float f) {
    unsigned u = __float_as_uint(f);
    return (u & 0x80000000u) ? ~u : (u | 0x80000000u);
}
__device__ __forceinline__ float dec(unsigned u) {
    return (u & 0x80000000u) ? __uint_as_float(u & 0x7fffffffu)
                             : __uint_as_float(~u);
}

// ---------------------------------------------------------------------------
// h0 GEMM: C[M][64] = relu(A[M][64] @ W[64][64] + bias)
// ---------------------------------------------------------------------------
__global__ __launch_bounds__(256) void gemm_h0(
    const float* __restrict__ A, const float* __restrict__ W,
    const float* __restrict__ bias, float* __restrict__ C, int M)
{
    __shared__ __align__(16) float Ws[64 * 64];
    __shared__ __align__(16) float As[64 * 68];

    const int t = threadIdx.x;
    const int m0 = blockIdx.x * 64;

    for (int i = t; i < 64 * 64; i += 256) Ws[i] = W[i];
    for (int rr = 0; rr < 64; rr += 16) {
        int r = rr + (t >> 4);
        int c4 = (t & 15) * 4;
        int row = m0 + r;
        float4 v = make_float4(0.f, 0.f, 0.f, 0.f);
        if (row < M) v = *(const float4*)&A[(size_t)row * 64 + c4];
        *(float4*)&As[r * 68 + c4] = v;
    }
    __syncthreads();

    const int tc = t & 15, tr = t >> 4;
    float4 acc[4];
    float4 bv = *(const float4*)&bias[tc * 4];
#pragma unroll
    for (int i = 0; i < 4; ++i) acc[i] = bv;
#pragma unroll 8
    for (int k = 0; k < 64; ++k) {
        float4 w = *(const float4*)&Ws[k * 64 + tc * 4];
#pragma unroll
        for (int i = 0; i < 4; ++i) {
            float a = As[(tr + i * 16) * 68 + k];
            acc[i].x = fmaf(a, w.x, acc[i].x);
            acc[i].y = fmaf(a, w.y, acc[i].y);
            acc[i].z = fmaf(a, w.z, acc[i].z);
            acc[i].w = fmaf(a, w.w, acc[i].w);
        }
    }
#pragma unroll
    for (int i = 0; i < 4; ++i) {
        int row = m0 + tr + i * 16;
        if (row < M) {
            float4 o = acc[i];
            o.x = fmaxf(o.x, 0.f); o.y = fmaxf(o.y, 0.f);
            o.z = fmaxf(o.z, 0.f); o.w = fmaxf(o.w, 0.f);
            *(float4*)&C[(size_t)row * 64 + tc * 4] = o;
        }
    }
}

// ---------------------------------------------------------------------------
// Fused p|q GEMM, f16 out, optional BN+relu on A-load.
// ---------------------------------------------------------------------------
template<bool BN>
__global__ __launch_bounds__(256) void gemm_pq(
    const float* __restrict__ A, const float* __restrict__ W,
    _Float16* __restrict__ PQ, const float* __restrict__ stats,
    const float* __restrict__ gamma, const float* __restrict__ beta, int M)
{
    __shared__ __align__(16) float Ws[64 * 128];
    __shared__ __align__(16) float As[64 * 68];

    const int t = threadIdx.x;
    const int m0 = blockIdx.x * 64;

    for (int i = t; i < 64 * 128; i += 256) {
        int k = i >> 7, n = i & 127;
        Ws[i] = W[(size_t)((n < 64 ? k : 64 + k)) * 64 + (n & 63)];
    }
    {
        int c4 = (t & 15) * 4;
        float sc[4], sh[4];
        if (BN) {
            float invM = 1.f / (float)M;
#pragma unroll
            for (int j = 0; j < 4; ++j) {
                int c = c4 + j;
                float mu = stats[c] * invM;
                float var = fmaxf(stats[64 + c] * invM - mu * mu, 0.f);
                float s = gamma[c] * rsqrtf(var + BN_EPS);
                sc[j] = s; sh[j] = beta[c] - mu * s;
            }
        }
        for (int rr = 0; rr < 64; rr += 16) {
            int r = rr + (t >> 4);
            int row = m0 + r;
            float4 v = make_float4(0.f, 0.f, 0.f, 0.f);
            if (row < M) v = *(const float4*)&A[(size_t)row * 64 + c4];
            if (BN) {
                v.x = fmaxf(fmaf(v.x, sc[0], sh[0]), 0.f);
                v.y = fmaxf(fmaf(v.y, sc[1], sh[1]), 0.f);
                v.z = fmaxf(fmaf(v.z, sc[2], sh[2]), 0.f);
                v.w = fmaxf(fmaf(v.w, sc[3], sh[3]), 0.f);
            }
            *(float4*)&As[r * 68 + c4] = v;
        }
    }
    __syncthreads();

    const int tc = t & 31, tr = t >> 5;
    float4 acc[8];
#pragma unroll
    for (int i = 0; i < 8; ++i) acc[i] = make_float4(0.f, 0.f, 0.f, 0.f);
#pragma unroll 8
    for (int k = 0; k < 64; ++k) {
        float4 w = *(const float4*)&Ws[k * 128 + tc * 4];
#pragma unroll
        for (int i = 0; i < 8; ++i) {
            float a = As[(tr + i * 8) * 68 + k];
            acc[i].x = fmaf(a, w.x, acc[i].x);
            acc[i].y = fmaf(a, w.y, acc[i].y);
            acc[i].z = fmaf(a, w.z, acc[i].z);
            acc[i].w = fmaf(a, w.w, acc[i].w);
        }
    }
#pragma unroll
    for (int i = 0; i < 8; ++i) {
        int row = m0 + tr + i * 8;
        if (row < M) {
            half4 o = { (_Float16)acc[i].x, (_Float16)acc[i].y,
                        (_Float16)acc[i].z, (_Float16)acc[i].w };
            *(half4*)&PQ[(size_t)row * 128 + tc * 4] = o;
        }
    }
}

// ---------------------------------------------------------------------------
// Fused head: out = relu(BN(h) @ w_m1 + b_m1) @ w_m2 + b_m2
// ---------------------------------------------------------------------------
__global__ __launch_bounds__(256) void head_fused(
    const float* __restrict__ hagg, const float* __restrict__ stats,
    const float* __restrict__ gamma, const float* __restrict__ beta,
    const float* __restrict__ w_m1, const float* __restrict__ b_m1,
    const float* __restrict__ w_m2, const float* __restrict__ b_m2,
    float* __restrict__ out, int M)
{
    __shared__ __align__(16) float Ws1[64 * 64];
    __shared__ __align__(16) float Ws2[64 * 32];
    __shared__ __align__(16) float As[64 * 68];
    __shared__ __align__(16) float Ts[64 * 68];

    const int t = threadIdx.x;
    const int m0 = blockIdx.x * 64;

    for (int i = t; i < 64 * 64; i += 256) Ws1[i] = w_m1[i];
    for (int i = t; i < 64 * 32; i += 256) Ws2[i] = w_m2[i];
    {
        int c4 = (t & 15) * 4;
        float sc[4], sh[4];
        float invM = 1.f / (float)M;
#pragma unroll
        for (int j = 0; j < 4; ++j) {
            int c = c4 + j;
            float mu = stats[c] * invM;
            float var = fmaxf(stats[64 + c] * invM - mu * mu, 0.f);
            float s = gamma[c] * rsqrtf(var + BN_EPS);
            sc[j] = s; sh[j] = beta[c] - mu * s;
        }
        for (int rr = 0; rr < 64; rr += 16) {
            int r = rr + (t >> 4);
            int row = m0 + r;
            float4 v = make_float4(0.f, 0.f, 0.f, 0.f);
            if (row < M) v = *(const float4*)&hagg[(size_t)row * 64 + c4];
            v.x = fmaxf(fmaf(v.x, sc[0], sh[0]), 0.f);
            v.y = fmaxf(fmaf(v.y, sc[1], sh[1]), 0.f);
            v.z = fmaxf(fmaf(v.z, sc[2], sh[2]), 0.f);
            v.w = fmaxf(fmaf(v.w, sc[3], sh[3]), 0.f);
            *(float4*)&As[r * 68 + c4] = v;
        }
    }
    __syncthreads();

    {
        const int tc = t & 15, tr = t >> 4;
        float4 acc[4];
        float4 bv = *(const float4*)&b_m1[tc * 4];
#pragma unroll
        for (int i = 0; i < 4; ++i) acc[i] = bv;
#pragma unroll 8
        for (int k = 0; k < 64; ++k) {
            float4 w = *(const float4*)&Ws1[k * 64 + tc * 4];
#pragma unroll
            for (int i = 0; i < 4; ++i) {
                float a = As[(tr + i * 16) * 68 + k];
                acc[i].x = fmaf(a, w.x, acc[i].x);
                acc[i].y = fmaf(a, w.y, acc[i].y);
                acc[i].z = fmaf(a, w.z, acc[i].z);
                acc[i].w = fmaf(a, w.w, acc[i].w);
            }
        }
#pragma unroll
        for (int i = 0; i < 4; ++i) {
            float4 o = acc[i];
            o.x = fmaxf(o.x, 0.f); o.y = fmaxf(o.y, 0.f);
            o.z = fmaxf(o.z, 0.f); o.w = fmaxf(o.w, 0.f);
            *(float4*)&Ts[(tr + i * 16) * 68 + tc * 4] = o;
        }
    }
    __syncthreads();

    {
        const int tc = t & 7, tr = t >> 3;
        float4 acc[2];
        float4 bv = *(const float4*)&b_m2[tc * 4];
        acc[0] = bv; acc[1] = bv;
#pragma unroll 8
        for (int k = 0; k < 64; ++k) {
            float4 w = *(const float4*)&Ws2[k * 32 + tc * 4];
#pragma unroll
            for (int i = 0; i < 2; ++i) {
                float a = Ts[(tr + i * 32) * 68 + k];
                acc[i].x = fmaf(a, w.x, acc[i].x);
                acc[i].y = fmaf(a, w.y, acc[i].y);
                acc[i].z = fmaf(a, w.z, acc[i].z);
                acc[i].w = fmaf(a, w.w, acc[i].w);
            }
        }
#pragma unroll
        for (int i = 0; i < 2; ++i) {
            int row = m0 + tr + i * 32;
            if (row < M) *(float4*)&out[(size_t)row * 32 + tc * 4] = acc[i];
        }
    }
}

// ---------------------------------------------------------------------------
// CSR build: hist -> multi-block exclusive scan -> fill(perm + srcp)
// ---------------------------------------------------------------------------
__global__ __launch_bounds__(256) void hist_tgt(const int* __restrict__ tgt,
                                                int* __restrict__ cnt, int E)
{
    int e = blockIdx.x * 256 + threadIdx.x;
    if (e < E) atomicAdd(&cnt[tgt[e]], 1);
}

__global__ __launch_bounds__(256) void scan_partial(const int* __restrict__ cnt,
                                                    int* __restrict__ part, int M)
{
    __shared__ int s[256];
    int i = blockIdx.x * 256 + threadIdx.x;
    s[threadIdx.x] = (i < M) ? cnt[i] : 0;
    __syncthreads();
    for (int off = 128; off > 0; off >>= 1) {
        if (threadIdx.x < off) s[threadIdx.x] += s[threadIdx.x + off];
        __syncthreads();
    }
    if (threadIdx.x == 0) part[blockIdx.x] = s[0];
}

__global__ __launch_bounds__(256) void scan_part2(int* __restrict__ part, int nb)
{
    __shared__ int s[256];
    int t = threadIdx.x;
    int v = (t < nb) ? part[t] : 0;
    s[t] = v;
    __syncthreads();
    for (int off = 1; off < 256; off <<= 1) {
        int a = (t >= off) ? s[t - off] : 0;
        __syncthreads();
        s[t] += a;
        __syncthreads();
    }
    if (t < nb) part[t] = s[t] - v;   // exclusive
}

__global__ __launch_bounds__(256) void scan_add(int* __restrict__ cnt,
                                                const int* __restrict__ part, int M)
{
    __shared__ int s[256];
    int t = threadIdx.x;
    int i = blockIdx.x * 256 + t;
    int v = (i < M) ? cnt[i] : 0;
    s[t] = v;
    __syncthreads();
    for (int off = 1; off < 256; off <<= 1) {
        int a = (t >= off) ? s[t - off] : 0;
        __syncthreads();
        s[t] += a;
        __syncthreads();
    }
    if (i < M) cnt[i] = part[blockIdx.x] + s[t] - v;
}

__global__ __launch_bounds__(256) void fill_csr(const int* __restrict__ tgt,
    const int* __restrict__ src, int* __restrict__ arr,
    int* __restrict__ perm, int* __restrict__ srcp, int E)
{
    int e = blockIdx.x * 256 + threadIdx.x;
    if (e < E) {
        int pos = atomicAdd(&arr[tgt[e]], 1);
        perm[pos] = e;
        srcp[pos] = src[e];
    }
}

// ---------------------------------------------------------------------------
// Pack w2 into f16 MFMA B-frag order; also zero the BN stats accumulators.
// ---------------------------------------------------------------------------
__global__ __launch_bounds__(256) void pack_w2(const float* __restrict__ w2,
                                               _Float16* __restrict__ w2h,
                                               float* __restrict__ stats)
{
    int id = blockIdx.x * 256 + threadIdx.x;
    if (id < 256) stats[id] = 0.f;
    if (id >= 1024) return;
    int l = id >> 9, rem = id & 511;
    int frag = rem >> 6, lane = rem & 63;
    int nt = frag >> 1, kc = frag & 1;
    const float* W = w2 + (size_t)l * 4096;
    _Float16* O = w2h + (size_t)l * 4096 + (frag * 64 + lane) * 8;
    int n = nt * 16 + (lane & 15);
    int k0 = kc * 32 + (lane >> 4) * 8;
#pragma unroll
    for (int j = 0; j < 8; ++j) O[j] = (_Float16)W[(k0 + j) * 64 + n];
}

// ---------------------------------------------------------------------------
// Fused per-node edge-MLP + segmented max + BN stats.
//   R11: NPB=16, ET=128, single merged load phase with batched issue,
//   srcp read in-place (wave-broadcast), w1c column in registers,
//   4 blocks/CU residency.
// ---------------------------------------------------------------------------
#define NPB 16
#define ET  128
#define TSH 72     // t1/q stride in halfs (144 B -> 2-way b128, free)

__global__ __launch_bounds__(256, 4) void node_agg(
    const _Float16* __restrict__ pq, const float* __restrict__ ea,
    const int* __restrict__ ends, const int* __restrict__ perm,
    const int* __restrict__ srcp,
    const float* __restrict__ w1c, const float* __restrict__ b1,
    const _Float16* __restrict__ w2h, const float* __restrict__ b2,
    float* __restrict__ hout, float* __restrict__ stats, int M)
{
    __shared__ __align__(16) _Float16 t1h[ET * TSH];   // 18.0 KB (q, then t1)
    __shared__ __align__(16) float eas[ET * 16];       //  8.0 KB
    __shared__ __align__(16) float ps[NPB * 64];       //  4.0 KB
    __shared__ __align__(16) unsigned rmu[NPB * 68];   //  4.25 KB
    __shared__ int endsL[NPB + 1];
    __shared__ unsigned char lnodS[ET];
    // total ~34.5 KB -> 4 blocks/CU

    const int t = threadIdx.x;
    const int lane = t & 63;
    const int wid = t >> 6;
    const int n0 = blockIdx.x * NPB;
    const int c = lane;

    // w1c column for this lane's channel: 16 regs (same for all 4 waves)
    float w1r[16];
#pragma unroll
    for (int j = 0; j < 16; ++j) w1r[j] = w1c[j * 64 + c];

    if (t <= NPB) {
        int n = n0 + t - 1;
        endsL[t] = (t == 0) ? ((n0 == 0) ? 0 : ends[n0 - 1])
                            : ((n < M) ? ends[n] : ends[M - 1]);
    }
    for (int nn = wid; nn < NPB; nn += 4) {
        int node = n0 + nn;
        ps[nn * 64 + c] =
            ((node < M) ? (float)pq[(size_t)node * 128 + c] : 0.f) + b1[c];
    }
    for (int i = t; i < NPB * 68; i += 256) rmu[i] = 0u;   // 0 < enc(anything)

    half8 bfrag[4][2];
#pragma unroll
    for (int nt = 0; nt < 4; ++nt)
#pragma unroll
        for (int kc = 0; kc < 2; ++kc)
            bfrag[nt][kc] = *(const half8*)(w2h + ((nt * 2 + kc) * 64 + lane) * 8);

    __syncthreads();

    const int eBeg = endsL[0], eEnd = endsL[NPB];

    for (int tile = eBeg; tile < eEnd; tile += ET) {
        const int cnt = min(ET, eEnd - tile);

        // ---- AB: metadata + ALL global loads, batched issue ----
        if (t < ET) {
            unsigned char L = 0;
            if (t < cnt) {
                int gp = tile + t;
                while (gp >= endsL[L + 1]) ++L;
            }
            lnodS[t] = L;
        }
        // edge_attr: 2 independent perm loads, then 2 ea float4 loads
        int pe[2];
#pragma unroll
        for (int r = 0; r < 2; ++r) {
            int i4 = t + r * 256;
            int ei = i4 >> 2;
            pe[r] = (ei < cnt) ? perm[tile + ei] : 0;
        }
        float4 eav[2];
#pragma unroll
        for (int r = 0; r < 2; ++r) {
            int i4 = t + r * 256;
            int j4 = i4 & 3;
            eav[r] = *(const float4*)&ea[(size_t)pe[r] * 16 + j4 * 4];
        }
        // q gather: 4 independent srcp loads (8 lanes/edge share one word ->
        // wave-broadcast), then 4 independent q half8 loads
        int sid[4];
        const int tot8 = cnt * 8;
#pragma unroll
        for (int r = 0; r < 4; ++r) {
            int i8 = t + r * 256;
            int ei = i8 >> 3;
            sid[r] = (i8 < tot8) ? srcp[tile + ei] : 0;
        }
        half8 qv[4];
#pragma unroll
        for (int r = 0; r < 4; ++r) {
            int i8 = t + r * 256, sub = i8 & 7;
            qv[r] = *(const half8*)&pq[(size_t)sid[r] * 128 + 64 + sub * 8];
        }
        // LDS stores
#pragma unroll
        for (int r = 0; r < 2; ++r) {
            int i4 = t + r * 256;
            int ei = i4 >> 2, j4 = i4 & 3;
            if (ei < cnt) *(float4*)&eas[ei * 16 + j4 * 4] = eav[r];
        }
#pragma unroll
        for (int r = 0; r < 4; ++r) {
            int i8 = t + r * 256;
            int ei = i8 >> 3, sub = i8 & 7;
            if (i8 < tot8) *(half8*)&t1h[ei * TSH + sub * 8] = qv[r];
        }
        __syncthreads();

        // ---- C: t1 = relu(p[tgt]+b1 + q + ea@w1c), in place ----
        for (int i = wid; i < cnt; i += 4) {
            float acc = ps[lnodS[i] * 64 + c] + (float)t1h[i * TSH + c];
#pragma unroll
            for (int j4 = 0; j4 < 4; ++j4) {
                float4 ev = *(const float4*)&eas[i * 16 + j4 * 4];
                acc = fmaf(ev.x, w1r[j4 * 4 + 0], acc);
                acc = fmaf(ev.y, w1r[j4 * 4 + 1], acc);
                acc = fmaf(ev.z, w1r[j4 * 4 + 2], acc);
                acc = fmaf(ev.w, w1r[j4 * 4 + 3], acc);
            }
            t1h[i * TSH + c] = (_Float16)fmaxf(acc, 0.f);
        }
        __syncthreads();

        // ---- D: m = t1 @ w2 via MFMA, segmented max into rmu ----
        {
            const int quad = lane >> 4;
            const int col = lane & 15;
            for (int mt = wid; mt * 16 < cnt; mt += 4) {
                const int e0 = mt * 16;
                floatx4 acc[4] = {{0.f,0.f,0.f,0.f},{0.f,0.f,0.f,0.f},
                                  {0.f,0.f,0.f,0.f},{0.f,0.f,0.f,0.f}};
#pragma unroll
                for (int kc = 0; kc < 2; ++kc) {
                    half8 a = *(const half8*)&t1h[(e0 + col) * TSH + kc * 32 + quad * 8];
#pragma unroll
                    for (int nt = 0; nt < 4; ++nt)
                        acc[nt] = __builtin_amdgcn_mfma_f32_16x16x32_f16(
                            a, bfrag[nt][kc], acc[nt], 0, 0, 0);
                }
                const int r0 = e0 + quad * 4;
#pragma unroll
                for (int nt = 0; nt < 4; ++nt) {
                    int curL = -1;
                    float best = 0.f;
#pragma unroll
                    for (int r = 0; r < 4; ++r) {
                        int ge = r0 + r;
                        if (ge < cnt) {
                            int L = lnodS[ge];
                            float v = acc[nt][r];
                            if (L != curL) {
                                if (curL >= 0)
                                    atomicMax(&rmu[curL * 68 + nt * 16 + col], enc(best));
                                curL = L; best = v;
                            } else best = fmaxf(best, v);
                        }
                    }
                    if (curL >= 0)
                        atomicMax(&rmu[curL * 68 + nt * 16 + col], enc(best));
                }
            }
        }
        __syncthreads();
    }

    // ---- final store (+b2, raw agg; BN deferred to consumer) + BN stats ----
    for (int idx = t; idx < NPB * 64; idx += 256) {
        int L = idx >> 6, cc = idx & 63;
        int node = n0 + L;
        float v = 0.f;
        if (node < M) {
            if (endsL[L + 1] > endsL[L]) v = dec(rmu[L * 68 + cc]) + b2[cc];
            hout[(size_t)node * 64 + cc] = v;
        }
        ((float*)rmu)[L * 68 + cc] = v;   // own slot: no race
    }
    __syncthreads();
    if (t < 64) {
        float s = 0.f, s2 = 0.f;
#pragma unroll
        for (int L = 0; L < NPB; ++L) {
            float v = ((float*)rmu)[L * 68 + t];
            s += v;
            s2 = fmaf(v, v, s2);
        }
        atomicAdd(&stats[t], s);
        atomicAdd(&stats[64 + t], s2);
    }
}

// ---------------------------------------------------------------------------
extern "C" void kernel_launch(void* const* d_in, const int* in_sizes, int n_in,
                              void* d_out, int out_size, void* d_ws, size_t ws_size,
                              hipStream_t stream)
{
    const float* x     = (const float*)d_in[0];
    const int*   eidx  = (const int*)  d_in[1];
    const float* ea    = (const float*)d_in[2];
    const float* w_in  = (const float*)d_in[3];
    const float* b_in  = (const float*)d_in[4];
    const float* w1    = (const float*)d_in[5];
    const float* b1    = (const float*)d_in[6];
    const float* w2    = (const float*)d_in[7];
    const float* b2    = (const float*)d_in[8];
    const float* gamma = (const float*)d_in[9];
    const float* beta  = (const float*)d_in[10];
    const float* w_m1  = (const float*)d_in[11];
    const float* b_m1  = (const float*)d_in[12];
    const float* w_m2  = (const float*)d_in[13];
    const float* b_m2  = (const float*)d_in[14];

    const int M = in_sizes[0] / 64;   // n_nodes
    const int E = in_sizes[1] / 2;    // n_edges
    const int* src = eidx;            // edge_index[0]
    const int* tgt = eidx + E;        // edge_index[1] (aggregation target)

    // ws: hagg f32 | pqh f16 | ends | srcp | part | stats = 29.0 MB
    float* hagg   = (float*)d_ws;
    _Float16* pqh = (_Float16*)(hagg + (size_t)M * 64);
    int* ends     = (int*)(pqh + (size_t)M * 128);
    int* srcp     = ends + M;
    const int nb  = (M + 255) / 256;
    int* part     = srcp + E;
    float* stats  = (float*)(part + nb);
    // d_out scratch: perm[E] | w2h — dead before head writes d_out
    int* perm = (int*)d_out;
    _Float16* w2h = (_Float16*)((char*)d_out + (size_t)E * 4);

    dim3 blk(256);
    const int gm64 = (M + 63) / 64;
    const int gE   = (E + 255) / 256;

    // CSR build + weight pack (+stats zero)
    hipMemsetAsync(ends, 0, (size_t)M * 4, stream);
    hist_tgt<<<gE, blk, 0, stream>>>(tgt, ends, E);
    scan_partial<<<nb, blk, 0, stream>>>(ends, part, M);
    scan_part2<<<1, blk, 0, stream>>>(part, nb);
    scan_add<<<nb, blk, 0, stream>>>(ends, part, M);
    fill_csr<<<gE, blk, 0, stream>>>(tgt, src, ends, perm, srcp, E);
    pack_w2<<<4, blk, 0, stream>>>(w2, w2h, stats);

    // h0 = relu(x @ w_in + b_in)
    gemm_h0<<<gm64, blk, 0, stream>>>(x, w_in, b_in, hagg, M);

    for (int l = 0; l < 2; ++l) {
        const float* w1l = w1 + (size_t)l * 144 * 64;
        if (l == 0)
            gemm_pq<false><<<gm64, blk, 0, stream>>>(hagg, w1l, pqh,
                nullptr, nullptr, nullptr, M);
        else
            gemm_pq<true><<<gm64, blk, 0, stream>>>(hagg, w1l, pqh,
                stats, gamma, beta, M);
        node_agg<<<(M + NPB - 1) / NPB, blk, 0, stream>>>(pqh, ea,
            ends, perm, srcp,
            w1l + 128 * 64, b1 + l * 64, w2h + (size_t)l * 4096, b2 + l * 64,
            hagg, stats + l * 128, M);
    }

    // out = relu(BN1(h) @ w_m1 + b_m1) @ w_m2 + b_m2
    head_fused<<<gm64, blk, 0, stream>>>(hagg, stats + 128, gamma + 64, beta + 64,
        w_m1, b_m1, w_m2, b_m2, (float*)d_out, M);
}

// Round 4
// 530.691 us; speedup vs baseline: 1.4464x; 1.1028x over previous
//
#include <hip/hip_runtime.h>
#include <float.h>

// ---------------------------------------------------------------------------
// MPNN forward.  msg@w1 decomposed: per-node p=h@w1a, q=h@w1b (fused gemm_pq,
// f16 out, BN fused on A-load), per-edge ea@w1c; edge GEMM t1@w2 f16 MFMA.
// R14 == R13 with the cvt_pkrtz type error fixed (plain scalar f16 converts
// for the exact hi/lo split; algorithm unchanged).
// R13: node_agg instruction-count attack (was issue-bound: ~93 instr/edge at
// 37% VALUBusy).  ea@w1c moved to MFMA with exact hi/lo f16 split (hi+lo
// reproduces f32; B = [w1c;w1c] K=32 packed in w1ch), C-in = ps+q built in
// MFMA C-layout -> old per-edge phase C (35 instr/edge) deleted.  C' and D
// fused per-wave (in-order DS pipe) -> 2 barriers/tile.  AB: waves 0-1 gather
// q 4-thr/edge (1 srcp load each, immediate-offset 16B ld/st) + 4-step binary
// search for lnodS; waves 2-3 gather ea + hi/lo split.  ps stride 68.
//
// ws (proven bound 38,601,024 B): hagg 12.8M | pqh 12.8M | ends 200K |
//   srcp 3.2M | part | stats(256f)  = 29.0 MB.
// d_out scratch: perm 3.2M | w2h 16K | w1ch 8K (dead before head writes).
// ---------------------------------------------------------------------------

typedef _Float16 half8 __attribute__((ext_vector_type(8)));
typedef _Float16 half4 __attribute__((ext_vector_type(4)));
typedef float floatx4 __attribute__((ext_vector_type(4)));

#define BN_EPS 1e-5f

__device__ __forceinline__ unsigned enc(float f) {
    unsigned u = __float_as_uint(f);
    return (u & 0x80000000u) ? ~u : (u | 0x80000000u);
}
__device__ __forceinline__ float dec(unsigned u) {
    return (u & 0x80000000u) ? __uint_as_float(u & 0x7fffffffu)
                             : __uint_as_float(~u);
}

// ---------------------------------------------------------------------------
// h0 GEMM: C[M][64] = relu(A[M][64] @ W[64][64] + bias)
// ---------------------------------------------------------------------------
__global__ __launch_bounds__(256) void gemm_h0(
    const float* __restrict__ A, const float* __restrict__ W,
    const float* __restrict__ bias, float* __restrict__ C, int M)
{
    __shared__ __align__(16) float Ws[64 * 64];
    __shared__ __align__(16) float As[64 * 68];

    const int t = threadIdx.x;
    const int m0 = blockIdx.x * 64;

    for (int i = t; i < 64 * 64; i += 256) Ws[i] = W[i];
    for (int rr = 0; rr < 64; rr += 16) {
        int r = rr + (t >> 4);
        int c4 = (t & 15) * 4;
        int row = m0 + r;
        float4 v = make_float4(0.f, 0.f, 0.f, 0.f);
        if (row < M) v = *(const float4*)&A[(size_t)row * 64 + c4];
        *(float4*)&As[r * 68 + c4] = v;
    }
    __syncthreads();

    const int tc = t & 15, tr = t >> 4;
    float4 acc[4];
    float4 bv = *(const float4*)&bias[tc * 4];
#pragma unroll
    for (int i = 0; i < 4; ++i) acc[i] = bv;
#pragma unroll 8
    for (int k = 0; k < 64; ++k) {
        float4 w = *(const float4*)&Ws[k * 64 + tc * 4];
#pragma unroll
        for (int i = 0; i < 4; ++i) {
            float a = As[(tr + i * 16) * 68 + k];
            acc[i].x = fmaf(a, w.x, acc[i].x);
            acc[i].y = fmaf(a, w.y, acc[i].y);
            acc[i].z = fmaf(a, w.z, acc[i].z);
            acc[i].w = fmaf(a, w.w, acc[i].w);
        }
    }
#pragma unroll
    for (int i = 0; i < 4; ++i) {
        int row = m0 + tr + i * 16;
        if (row < M) {
            float4 o = acc[i];
            o.x = fmaxf(o.x, 0.f); o.y = fmaxf(o.y, 0.f);
            o.z = fmaxf(o.z, 0.f); o.w = fmaxf(o.w, 0.f);
            *(float4*)&C[(size_t)row * 64 + tc * 4] = o;
        }
    }
}

// ---------------------------------------------------------------------------
// Fused p|q GEMM, f16 out, optional BN+relu on A-load.
// ---------------------------------------------------------------------------
template<bool BN>
__global__ __launch_bounds__(256) void gemm_pq(
    const float* __restrict__ A, const float* __restrict__ W,
    _Float16* __restrict__ PQ, const float* __restrict__ stats,
    const float* __restrict__ gamma, const float* __restrict__ beta, int M)
{
    __shared__ __align__(16) float Ws[64 * 128];
    __shared__ __align__(16) float As[64 * 68];

    const int t = threadIdx.x;
    const int m0 = blockIdx.x * 64;

    for (int i = t; i < 64 * 128; i += 256) {
        int k = i >> 7, n = i & 127;
        Ws[i] = W[(size_t)((n < 64 ? k : 64 + k)) * 64 + (n & 63)];
    }
    {
        int c4 = (t & 15) * 4;
        float sc[4], sh[4];
        if (BN) {
            float invM = 1.f / (float)M;
#pragma unroll
            for (int j = 0; j < 4; ++j) {
                int c = c4 + j;
                float mu = stats[c] * invM;
                float var = fmaxf(stats[64 + c] * invM - mu * mu, 0.f);
                float s = gamma[c] * rsqrtf(var + BN_EPS);
                sc[j] = s; sh[j] = beta[c] - mu * s;
            }
        }
        for (int rr = 0; rr < 64; rr += 16) {
            int r = rr + (t >> 4);
            int row = m0 + r;
            float4 v = make_float4(0.f, 0.f, 0.f, 0.f);
            if (row < M) v = *(const float4*)&A[(size_t)row * 64 + c4];
            if (BN) {
                v.x = fmaxf(fmaf(v.x, sc[0], sh[0]), 0.f);
                v.y = fmaxf(fmaf(v.y, sc[1], sh[1]), 0.f);
                v.z = fmaxf(fmaf(v.z, sc[2], sh[2]), 0.f);
                v.w = fmaxf(fmaf(v.w, sc[3], sh[3]), 0.f);
            }
            *(float4*)&As[r * 68 + c4] = v;
        }
    }
    __syncthreads();

    const int tc = t & 31, tr = t >> 5;
    float4 acc[8];
#pragma unroll
    for (int i = 0; i < 8; ++i) acc[i] = make_float4(0.f, 0.f, 0.f, 0.f);
#pragma unroll 8
    for (int k = 0; k < 64; ++k) {
        float4 w = *(const float4*)&Ws[k * 128 + tc * 4];
#pragma unroll
        for (int i = 0; i < 8; ++i) {
            float a = As[(tr + i * 8) * 68 + k];
            acc[i].x = fmaf(a, w.x, acc[i].x);
            acc[i].y = fmaf(a, w.y, acc[i].y);
            acc[i].z = fmaf(a, w.z, acc[i].z);
            acc[i].w = fmaf(a, w.w, acc[i].w);
        }
    }
#pragma unroll
    for (int i = 0; i < 8; ++i) {
        int row = m0 + tr + i * 8;
        if (row < M) {
            half4 o = { (_Float16)acc[i].x, (_Float16)acc[i].y,
                        (_Float16)acc[i].z, (_Float16)acc[i].w };
            *(half4*)&PQ[(size_t)row * 128 + tc * 4] = o;
        }
    }
}

// ---------------------------------------------------------------------------
// Fused head: out = relu(BN(h) @ w_m1 + b_m1) @ w_m2 + b_m2
// ---------------------------------------------------------------------------
__global__ __launch_bounds__(256) void head_fused(
    const float* __restrict__ hagg, const float* __restrict__ stats,
    const float* __restrict__ gamma, const float* __restrict__ beta,
    const float* __restrict__ w_m1, const float* __restrict__ b_m1,
    const float* __restrict__ w_m2, const float* __restrict__ b_m2,
    float* __restrict__ out, int M)
{
    __shared__ __align__(16) float Ws1[64 * 64];
    __shared__ __align__(16) float Ws2[64 * 32];
    __shared__ __align__(16) float As[64 * 68];
    __shared__ __align__(16) float Ts[64 * 68];

    const int t = threadIdx.x;
    const int m0 = blockIdx.x * 64;

    for (int i = t; i < 64 * 64; i += 256) Ws1[i] = w_m1[i];
    for (int i = t; i < 64 * 32; i += 256) Ws2[i] = w_m2[i];
    {
        int c4 = (t & 15) * 4;
        float sc[4], sh[4];
        float invM = 1.f / (float)M;
#pragma unroll
        for (int j = 0; j < 4; ++j) {
            int c = c4 + j;
            float mu = stats[c] * invM;
            float var = fmaxf(stats[64 + c] * invM - mu * mu, 0.f);
            float s = gamma[c] * rsqrtf(var + BN_EPS);
            sc[j] = s; sh[j] = beta[c] - mu * s;
        }
        for (int rr = 0; rr < 64; rr += 16) {
            int r = rr + (t >> 4);
            int row = m0 + r;
            float4 v = make_float4(0.f, 0.f, 0.f, 0.f);
            if (row < M) v = *(const float4*)&hagg[(size_t)row * 64 + c4];
            v.x = fmaxf(fmaf(v.x, sc[0], sh[0]), 0.f);
            v.y = fmaxf(fmaf(v.y, sc[1], sh[1]), 0.f);
            v.z = fmaxf(fmaf(v.z, sc[2], sh[2]), 0.f);
            v.w = fmaxf(fmaf(v.w, sc[3], sh[3]), 0.f);
            *(float4*)&As[r * 68 + c4] = v;
        }
    }
    __syncthreads();

    {
        const int tc = t & 15, tr = t >> 4;
        float4 acc[4];
        float4 bv = *(const float4*)&b_m1[tc * 4];
#pragma unroll
        for (int i = 0; i < 4; ++i) acc[i] = bv;
#pragma unroll 8
        for (int k = 0; k < 64; ++k) {
            float4 w = *(const float4*)&Ws1[k * 64 + tc * 4];
#pragma unroll
            for (int i = 0; i < 4; ++i) {
                float a = As[(tr + i * 16) * 68 + k];
                acc[i].x = fmaf(a, w.x, acc[i].x);
                acc[i].y = fmaf(a, w.y, acc[i].y);
                acc[i].z = fmaf(a, w.z, acc[i].z);
                acc[i].w = fmaf(a, w.w, acc[i].w);
            }
        }
#pragma unroll
        for (int i = 0; i < 4; ++i) {
            float4 o = acc[i];
            o.x = fmaxf(o.x, 0.f); o.y = fmaxf(o.y, 0.f);
            o.z = fmaxf(o.z, 0.f); o.w = fmaxf(o.w, 0.f);
            *(float4*)&Ts[(tr + i * 16) * 68 + tc * 4] = o;
        }
    }
    __syncthreads();

    {
        const int tc = t & 7, tr = t >> 3;
        float4 acc[2];
        float4 bv = *(const float4*)&b_m2[tc * 4];
        acc[0] = bv; acc[1] = bv;
#pragma unroll 8
        for (int k = 0; k < 64; ++k) {
            float4 w = *(const float4*)&Ws2[k * 32 + tc * 4];
#pragma unroll
            for (int i = 0; i < 2; ++i) {
                float a = Ts[(tr + i * 32) * 68 + k];
                acc[i].x = fmaf(a, w.x, acc[i].x);
                acc[i].y = fmaf(a, w.y, acc[i].y);
                acc[i].z = fmaf(a, w.z, acc[i].z);
                acc[i].w = fmaf(a, w.w, acc[i].w);
            }
        }
#pragma unroll
        for (int i = 0; i < 2; ++i) {
            int row = m0 + tr + i * 32;
            if (row < M) *(float4*)&out[(size_t)row * 32 + tc * 4] = acc[i];
        }
    }
}

// ---------------------------------------------------------------------------
// CSR build: hist -> multi-block exclusive scan -> fill(perm + srcp)
// ---------------------------------------------------------------------------
__global__ __launch_bounds__(256) void hist_tgt(const int* __restrict__ tgt,
                                                int* __restrict__ cnt, int E)
{
    int e = blockIdx.x * 256 + threadIdx.x;
    if (e < E) atomicAdd(&cnt[tgt[e]], 1);
}

__global__ __launch_bounds__(256) void scan_partial(const int* __restrict__ cnt,
                                                    int* __restrict__ part, int M)
{
    __shared__ int s[256];
    int i = blockIdx.x * 256 + threadIdx.x;
    s[threadIdx.x] = (i < M) ? cnt[i] : 0;
    __syncthreads();
    for (int off = 128; off > 0; off >>= 1) {
        if (threadIdx.x < off) s[threadIdx.x] += s[threadIdx.x + off];
        __syncthreads();
    }
    if (threadIdx.x == 0) part[blockIdx.x] = s[0];
}

__global__ __launch_bounds__(256) void scan_part2(int* __restrict__ part, int nb)
{
    __shared__ int s[256];
    int t = threadIdx.x;
    int v = (t < nb) ? part[t] : 0;
    s[t] = v;
    __syncthreads();
    for (int off = 1; off < 256; off <<= 1) {
        int a = (t >= off) ? s[t - off] : 0;
        __syncthreads();
        s[t] += a;
        __syncthreads();
    }
    if (t < nb) part[t] = s[t] - v;   // exclusive
}

__global__ __launch_bounds__(256) void scan_add(int* __restrict__ cnt,
                                                const int* __restrict__ part, int M)
{
    __shared__ int s[256];
    int t = threadIdx.x;
    int i = blockIdx.x * 256 + t;
    int v = (i < M) ? cnt[i] : 0;
    s[t] = v;
    __syncthreads();
    for (int off = 1; off < 256; off <<= 1) {
        int a = (t >= off) ? s[t - off] : 0;
        __syncthreads();
        s[t] += a;
        __syncthreads();
    }
    if (i < M) cnt[i] = part[blockIdx.x] + s[t] - v;
}

__global__ __launch_bounds__(256) void fill_csr(const int* __restrict__ tgt,
    const int* __restrict__ src, int* __restrict__ arr,
    int* __restrict__ perm, int* __restrict__ srcp, int E)
{
    int e = blockIdx.x * 256 + threadIdx.x;
    if (e < E) {
        int pos = atomicAdd(&arr[tgt[e]], 1);
        perm[pos] = e;
        srcp[pos] = src[e];
    }
}

// ---------------------------------------------------------------------------
// Pack w2 into f16 MFMA B-frag order; pack w1c as [w1c;w1c] K=32 B-frags
// (for the exact hi/lo-split ea MFMA); zero BN stats accumulators.
// ---------------------------------------------------------------------------
__global__ __launch_bounds__(256) void pack_w2(const float* __restrict__ w2,
                                               const float* __restrict__ w1,
                                               _Float16* __restrict__ w2h,
                                               _Float16* __restrict__ w1ch,
                                               float* __restrict__ stats)
{
    int id = blockIdx.x * 256 + threadIdx.x;
    if (id < 256) stats[id] = 0.f;
    if (id < 1024) {
        int l = id >> 9, rem = id & 511;
        int frag = rem >> 6, lane = rem & 63;
        int nt = frag >> 1, kc = frag & 1;
        const float* W = w2 + (size_t)l * 4096;
        _Float16* O = w2h + (size_t)l * 4096 + (frag * 64 + lane) * 8;
        int n = nt * 16 + (lane & 15);
        int k0 = kc * 32 + (lane >> 4) * 8;
#pragma unroll
        for (int j = 0; j < 8; ++j) O[j] = (_Float16)W[(k0 + j) * 64 + n];
    } else if (id < 1536) {
        // w1ch: B[k][n] = w1c[k & 15][n], K=32 (duplicated halves), 4 nt tiles
        int rem2 = id - 1024;
        int l = rem2 >> 8, rem = rem2 & 255;
        int nt = rem >> 6, lane = rem & 63;
        const float* W1C = w1 + (size_t)l * 144 * 64 + 128 * 64;
        _Float16* O = w1ch + (size_t)l * 2048 + (nt * 64 + lane) * 8;
        int n = nt * 16 + (lane & 15);
        int k0 = (lane >> 4) * 8;
#pragma unroll
        for (int j = 0; j < 8; ++j)
            O[j] = (_Float16)W1C[((k0 + j) & 15) * 64 + n];
    }
}

// ---------------------------------------------------------------------------
// Fused per-node edge-MLP + segmented max + BN stats.
//   R13/R14: ea@w1c via MFMA (exact hi/lo f16 split, C-in = ps+q), C'+D fused
//   per wave (in-order DS), AB 4-thr/edge q gather + binary-search lnodS.
// ---------------------------------------------------------------------------
#define NPB 16
#define ET  128
#define TSH 72     // t1/q stride in halfs (144 B -> 2-way b128, free)
#define EST 40     // eash stride in halfs (80 B, 16B-aligned rows, 2-way)

__global__ __launch_bounds__(256, 4) void node_agg(
    const _Float16* __restrict__ pq, const float* __restrict__ ea,
    const int* __restrict__ ends, const int* __restrict__ perm,
    const int* __restrict__ srcp,
    const _Float16* __restrict__ w1cbG, const float* __restrict__ b1,
    const _Float16* __restrict__ w2h, const float* __restrict__ b2,
    float* __restrict__ hout, float* __restrict__ stats, int M)
{
    __shared__ __align__(16) _Float16 t1h[ET * TSH];   // 18.0 KB (q, then t1)
    __shared__ __align__(16) _Float16 eash[ET * EST];  // 10.0 KB (hi|lo)
    __shared__ __align__(16) float ps[NPB * 68];       //  4.25 KB
    __shared__ __align__(16) unsigned rmu[NPB * 68];   //  4.25 KB
    __shared__ int endsL[NPB + 1];
    __shared__ unsigned char lnodS[ET];
    // total ~36.7 KB -> 4 blocks/CU

    const int t = threadIdx.x;
    const int lane = t & 63;
    const int wid = t >> 6;
    const int n0 = blockIdx.x * NPB;
    const int c = lane;

    if (t <= NPB) {
        int n = n0 + t - 1;
        endsL[t] = (t == 0) ? ((n0 == 0) ? 0 : ends[n0 - 1])
                            : ((n < M) ? ends[n] : ends[M - 1]);
    }
    for (int nn = wid; nn < NPB; nn += 4) {
        int node = n0 + nn;
        ps[nn * 68 + c] =
            ((node < M) ? (float)pq[(size_t)node * 128 + c] : 0.f) + b1[c];
    }
    for (int i = t; i < NPB * 68; i += 256) rmu[i] = 0u;   // 0 < enc(anything)

    half8 bfrag[4][2];
#pragma unroll
    for (int nt = 0; nt < 4; ++nt)
#pragma unroll
        for (int kc = 0; kc < 2; ++kc)
            bfrag[nt][kc] = *(const half8*)(w2h + ((nt * 2 + kc) * 64 + lane) * 8);
    half8 w1cb[4];
#pragma unroll
    for (int nt = 0; nt < 4; ++nt)
        w1cb[nt] = *(const half8*)(w1cbG + (nt * 64 + lane) * 8);

    __syncthreads();

    const int eBeg = endsL[0], eEnd = endsL[NPB];

    for (int tile = eBeg; tile < eEnd; tile += ET) {
        const int cnt = min(ET, eEnd - tile);

        // ---- AB: waves 0-1 gather q (4 thr/edge) + lnodS; waves 2-3 ea ----
        if (t < 128) {
            const int u = t;
            // lnodS[u]: binary search over endsL[0..NPB]
            if (u < cnt) {
                int gp = tile + u;
                int lo = 0, hi = NPB;
#pragma unroll
                for (int s = 0; s < 4; ++s) {
                    int mid = (lo + hi) >> 1;
                    bool ge = gp >= endsL[mid];
                    lo = ge ? mid : lo;
                    hi = ge ? hi : mid;
                }
                lnodS[u] = (unsigned char)lo;
            } else lnodS[u] = 0;
            // q rows: 4 threads/edge, 2x16B each, immediate offsets
#pragma unroll
            for (int r = 0; r < 4; ++r) {
                int cg = u + r * 128;
                int ei = cg >> 2, j2 = cg & 3;
                int sid = srcp[tile + ((ei < cnt) ? ei : 0)];
                const _Float16* qs = pq + (size_t)sid * 128 + 64 + j2 * 16;
                half8 a = *(const half8*)(qs);
                half8 b = *(const half8*)(qs + 8);
                _Float16* qd = t1h + ei * TSH + j2 * 16;
                *(half8*)qd = a;
                *(half8*)(qd + 8) = b;
            }
        } else {
            const int v = t - 128;
            // ea rows: 2 threads/edge, f32 -> exact hi/lo f16 split
#pragma unroll
            for (int r = 0; r < 2; ++r) {
                int hg = v + r * 128;
                int ei = hg >> 1, h = hg & 1;
                int pe = perm[tile + ((ei < cnt) ? ei : 0)];
                const float* es = ea + (size_t)pe * 16 + h * 8;
                float4 x = *(const float4*)(es);
                float4 y = *(const float4*)(es + 4);
                float xs[8] = { x.x, x.y, x.z, x.w, y.x, y.y, y.z, y.w };
                half8 hi8, lo8;
#pragma unroll
                for (int j = 0; j < 8; ++j) {
                    _Float16 hj = (_Float16)xs[j];
                    hi8[j] = hj;
                    lo8[j] = (_Float16)(xs[j] - (float)hj);
                }
                _Float16* ed = eash + ei * EST + h * 8;
                *(half8*)ed = hi8;          // hi block: halfs [0,16)
                *(half8*)(ed + 16) = lo8;   // lo block: halfs [16,32)
            }
        }
        __syncthreads();

        // ---- C'+D fused, per 16-edge group per wave ----
        {
            const int quad = lane >> 4;
            const int col = lane & 15;
            for (int mt = wid; mt * 16 < cnt; mt += 4) {
                const int e0 = mt * 16;
                const int ebase = e0 + quad * 4;
                const int L0 = lnodS[ebase + 0], L1 = lnodS[ebase + 1],
                          L2 = lnodS[ebase + 2], L3 = lnodS[ebase + 3];
                _Float16* qb = &t1h[ebase * TSH + col];
                const float* p0 = &ps[L0 * 68 + col];
                const float* p1 = &ps[L1 * 68 + col];
                const float* p2 = &ps[L2 * 68 + col];
                const float* p3 = &ps[L3 * 68 + col];
                // C-in = ps + q, in MFMA C-layout (row=quad*4+r, col=nt*16+col)
                floatx4 acc[4];
#pragma unroll
                for (int nt = 0; nt < 4; ++nt) {
                    acc[nt][0] = (float)qb[0 * TSH + nt * 16] + p0[nt * 16];
                    acc[nt][1] = (float)qb[1 * TSH + nt * 16] + p1[nt * 16];
                    acc[nt][2] = (float)qb[2 * TSH + nt * 16] + p2[nt * 16];
                    acc[nt][3] = (float)qb[3 * TSH + nt * 16] + p3[nt * 16];
                }
                // + ea @ w1c  (A = [hi|lo] K=32, B = [w1c;w1c])
                half8 af = *(const half8*)&eash[(e0 + col) * EST + quad * 8];
#pragma unroll
                for (int nt = 0; nt < 4; ++nt)
                    acc[nt] = __builtin_amdgcn_mfma_f32_16x16x32_f16(
                        af, w1cb[nt], acc[nt], 0, 0, 0);
                // t1 = relu(.) -> f16, written back in place (same wave reads)
#pragma unroll
                for (int nt = 0; nt < 4; ++nt) {
#pragma unroll
                    for (int r = 0; r < 4; ++r)
                        qb[r * TSH + nt * 16] =
                            (_Float16)fmaxf(acc[nt][r], 0.f);
                }
                // ---- D: m = t1 @ w2, segmented max into rmu ----
                floatx4 accD[4] = {{0.f,0.f,0.f,0.f},{0.f,0.f,0.f,0.f},
                                   {0.f,0.f,0.f,0.f},{0.f,0.f,0.f,0.f}};
#pragma unroll
                for (int kc = 0; kc < 2; ++kc) {
                    half8 a = *(const half8*)
                        &t1h[(e0 + col) * TSH + kc * 32 + quad * 8];
#pragma unroll
                    for (int nt = 0; nt < 4; ++nt)
                        accD[nt] = __builtin_amdgcn_mfma_f32_16x16x32_f16(
                            a, bfrag[nt][kc], accD[nt], 0, 0, 0);
                }
#pragma unroll
                for (int nt = 0; nt < 4; ++nt) {
                    int curL = -1;
                    float best = 0.f;
#pragma unroll
                    for (int r = 0; r < 4; ++r) {
                        int ge = ebase + r;
                        if (ge < cnt) {
                            int L = (r == 0) ? L0 : (r == 1) ? L1
                                  : (r == 2) ? L2 : L3;
                            float v = accD[nt][r];
                            if (L != curL) {
                                if (curL >= 0)
                                    atomicMax(&rmu[curL * 68 + nt * 16 + col],
                                              enc(best));
                                curL = L; best = v;
                            } else best = fmaxf(best, v);
                        }
                    }
                    if (curL >= 0)
                        atomicMax(&rmu[curL * 68 + nt * 16 + col], enc(best));
                }
            }
        }
        __syncthreads();
    }

    // ---- final store (+b2, raw agg; BN deferred to consumer) + BN stats ----
    for (int idx = t; idx < NPB * 64; idx += 256) {
        int L = idx >> 6, cc = idx & 63;
        int node = n0 + L;
        float v = 0.f;
        if (node < M) {
            if (endsL[L + 1] > endsL[L]) v = dec(rmu[L * 68 + cc]) + b2[cc];
            hout[(size_t)node * 64 + cc] = v;
        }
        ((float*)rmu)[L * 68 + cc] = v;   // own slot: no race
    }
    __syncthreads();
    if (t < 64) {
        float s = 0.f, s2 = 0.f;
#pragma unroll
        for (int L = 0; L < NPB; ++L) {
            float v = ((float*)rmu)[L * 68 + t];
            s += v;
            s2 = fmaf(v, v, s2);
        }
        atomicAdd(&stats[t], s);
        atomicAdd(&stats[64 + t], s2);
    }
}

// ---------------------------------------------------------------------------
extern "C" void kernel_launch(void* const* d_in, const int* in_sizes, int n_in,
                              void* d_out, int out_size, void* d_ws, size_t ws_size,
                              hipStream_t stream)
{
    const float* x     = (const float*)d_in[0];
    const int*   eidx  = (const int*)  d_in[1];
    const float* ea    = (const float*)d_in[2];
    const float* w_in  = (const float*)d_in[3];
    const float* b_in  = (const float*)d_in[4];
    const float* w1    = (const float*)d_in[5];
    const float* b1    = (const float*)d_in[6];
    const float* w2    = (const float*)d_in[7];
    const float* b2    = (const float*)d_in[8];
    const float* gamma = (const float*)d_in[9];
    const float* beta  = (const float*)d_in[10];
    const float* w_m1  = (const float*)d_in[11];
    const float* b_m1  = (const float*)d_in[12];
    const float* w_m2  = (const float*)d_in[13];
    const float* b_m2  = (const float*)d_in[14];

    const int M = in_sizes[0] / 64;   // n_nodes
    const int E = in_sizes[1] / 2;    // n_edges
    const int* src = eidx;            // edge_index[0]
    const int* tgt = eidx + E;        // edge_index[1] (aggregation target)

    // ws: hagg f32 | pqh f16 | ends | srcp | part | stats = 29.0 MB
    float* hagg   = (float*)d_ws;
    _Float16* pqh = (_Float16*)(hagg + (size_t)M * 64);
    int* ends     = (int*)(pqh + (size_t)M * 128);
    int* srcp     = ends + M;
    const int nb  = (M + 255) / 256;
    int* part     = srcp + E;
    float* stats  = (float*)(part + nb);
    // d_out scratch: perm[E] | w2h | w1ch — dead before head writes d_out
    int* perm = (int*)d_out;
    _Float16* w2h  = (_Float16*)((char*)d_out + (size_t)E * 4);
    _Float16* w1ch = (_Float16*)((char*)d_out + (size_t)E * 4 + 16384);

    dim3 blk(256);
    const int gm64 = (M + 63) / 64;
    const int gE   = (E + 255) / 256;

    // CSR build + weight pack (+stats zero)
    (void)hipMemsetAsync(ends, 0, (size_t)M * 4, stream);
    hist_tgt<<<gE, blk, 0, stream>>>(tgt, ends, E);
    scan_partial<<<nb, blk, 0, stream>>>(ends, part, M);
    scan_part2<<<1, blk, 0, stream>>>(part, nb);
    scan_add<<<nb, blk, 0, stream>>>(ends, part, M);
    fill_csr<<<gE, blk, 0, stream>>>(tgt, src, ends, perm, srcp, E);
    pack_w2<<<6, blk, 0, stream>>>(w2, w1, w2h, w1ch, stats);

    // h0 = relu(x @ w_in + b_in)
    gemm_h0<<<gm64, blk, 0, stream>>>(x, w_in, b_in, hagg, M);

    for (int l = 0; l < 2; ++l) {
        const float* w1l = w1 + (size_t)l * 144 * 64;
        if (l == 0)
            gemm_pq<false><<<gm64, blk, 0, stream>>>(hagg, w1l, pqh,
                nullptr, nullptr, nullptr, M);
        else
            gemm_pq<true><<<gm64, blk, 0, stream>>>(hagg, w1l, pqh,
                stats, gamma, beta, M);
        node_agg<<<(M + NPB - 1) / NPB, blk, 0, stream>>>(pqh, ea,
            ends, perm, srcp,
            w1ch + (size_t)l * 2048, b1 + l * 64,
            w2h + (size_t)l * 4096, b2 + l * 64,
            hagg, stats + l * 128, M);
    }

    // out = relu(BN1(h) @ w_m1 + b_m1) @ w_m2 + b_m2
    head_fused<<<gm64, blk, 0, stream>>>(hagg, stats + 128, gamma + 64, beta + 64,
        w_m1, b_m1, w_m2, b_m2, (float*)d_out, M);
}